// Round 1
// baseline (576.931 us; speedup 1.0000x reference)
//
#include <hip/hip_runtime.h>
#include <hip/hip_bf16.h>

typedef __bf16 bf16_t;
typedef __bf16 bf16x8 __attribute__((ext_vector_type(8)));
typedef float f32x4 __attribute__((ext_vector_type(4)));

static constexpr int BB    = 2;
static constexpr int SEQ   = 2048;
static constexpr int DM    = 1024;   // D == INNER
static constexpr int NHEAD = 16;
static constexpr int HD    = 64;

__device__ __forceinline__ bf16x8 ld8(const bf16_t* p) {
  return *reinterpret_cast<const bf16x8*>(p);
}

template <typename T> __device__ __forceinline__ T cvt_out(float v);
template <> __device__ __forceinline__ float  cvt_out<float >(float v) { return v; }
template <> __device__ __forceinline__ bf16_t cvt_out<bf16_t>(float v) { return (bf16_t)v; }

// ---------------- transpose + cast: in (R,C) fp32 -> out (C,R) bf16 ----------------
__global__ __launch_bounds__(256) void transpose_cast(const float* __restrict__ in,
                                                      bf16_t* __restrict__ out,
                                                      int R, int C) {
  __shared__ float tile[32][33];
  const int c0 = blockIdx.x * 32, r0 = blockIdx.y * 32;
  const int tx = threadIdx.x & 31, ty = threadIdx.x >> 5;
#pragma unroll
  for (int y = ty; y < 32; y += 8)
    tile[y][tx] = in[(size_t)(r0 + y) * C + (c0 + tx)];
  __syncthreads();
#pragma unroll
  for (int y = ty; y < 32; y += 8)
    out[(size_t)(c0 + y) * R + (r0 + tx)] = (bf16_t)tile[tx][y];
}

// ---------------- LayerNorm row kernel: emits x(bf16) and xn(bf16) ----------------
__global__ __launch_bounds__(256) void row_prep(const float* __restrict__ x,
    const float* __restrict__ ln_w, const float* __restrict__ ln_b,
    bf16_t* __restrict__ xbf, bf16_t* __restrict__ xn) {
  const int row = blockIdx.x, t = threadIdx.x;
  __shared__ float red[8];
  const float4 xv = *reinterpret_cast<const float4*>(&x[(size_t)row * DM + t * 4]);
  float s  = xv.x + xv.y + xv.z + xv.w;
  float s2 = xv.x * xv.x + xv.y * xv.y + xv.z * xv.z + xv.w * xv.w;
#pragma unroll
  for (int off = 32; off >= 1; off >>= 1) {
    s  += __shfl_xor(s,  off, 64);
    s2 += __shfl_xor(s2, off, 64);
  }
  if ((t & 63) == 0) { red[t >> 6] = s; red[4 + (t >> 6)] = s2; }
  __syncthreads();
  s  = red[0] + red[1] + red[2] + red[3];
  s2 = red[4] + red[5] + red[6] + red[7];
  const float mu   = s * (1.0f / DM);
  const float var  = s2 * (1.0f / DM) - mu * mu;
  const float rstd = rsqrtf(var + 1e-5f);
  const float4 wv = *reinterpret_cast<const float4*>(&ln_w[t * 4]);
  const float4 bv = *reinterpret_cast<const float4*>(&ln_b[t * 4]);
  union { bf16_t h[4]; uint2 u; } p0, p1;
  p0.h[0] = (bf16_t)xv.x; p0.h[1] = (bf16_t)xv.y;
  p0.h[2] = (bf16_t)xv.z; p0.h[3] = (bf16_t)xv.w;
  p1.h[0] = (bf16_t)((xv.x - mu) * rstd * wv.x + bv.x);
  p1.h[1] = (bf16_t)((xv.y - mu) * rstd * wv.y + bv.y);
  p1.h[2] = (bf16_t)((xv.z - mu) * rstd * wv.z + bv.z);
  p1.h[3] = (bf16_t)((xv.w - mu) * rstd * wv.w + bv.w);
  *reinterpret_cast<uint2*>(&xbf[(size_t)row * DM + t * 4]) = p0.u;
  *reinterpret_cast<uint2*>(&xn [(size_t)row * DM + t * 4]) = p1.u;
}

// ---------------- bf16 MFMA GEMM: C(M,Nn) = A(M,K) * Bt(Nn,K)^T ----------------
// 128x64 block tile, BK=32, 4 waves (each 64x32). If C2 != nullptr: kv-split
// epilogue (C=K as (B*SEQ,64), C2=V^T as (B,64,SEQ)).
template <typename OutT>
__global__ __launch_bounds__(256) void gemm_bt(const bf16_t* __restrict__ A,
    const bf16_t* __restrict__ Bt, OutT* __restrict__ C, OutT* __restrict__ C2,
    int M, int Nn, int K, float scale) {
  __shared__ alignas(16) bf16_t As[128][40];
  __shared__ alignas(16) bf16_t Bs[64][40];
  const int m0 = blockIdx.x * 128, n0 = blockIdx.y * 64;
  const int t = threadIdx.x, lane = t & 63, wv = t >> 6;
  const int wm = (wv >> 1) * 64, wn = (wv & 1) * 32;
  const int l15 = lane & 15, q4 = lane >> 4;
  f32x4 acc[4][2] = {};
  const int ar = t >> 1, ac = (t & 1) * 16;  // A: 128 rows x (2x16B)/thread
  const int br = t >> 2, bc = (t & 3) * 8;   // B: 64 rows x (1x16B)/thread
  const bf16_t* Ap = A  + (size_t)(m0 + ar) * K + ac;
  const bf16_t* Bp = Bt + (size_t)(n0 + br) * K + bc;
  for (int k0 = 0; k0 < K; k0 += 32) {
    *reinterpret_cast<uint4*>(&As[ar][ac])     = *reinterpret_cast<const uint4*>(Ap + k0);
    *reinterpret_cast<uint4*>(&As[ar][ac + 8]) = *reinterpret_cast<const uint4*>(Ap + k0 + 8);
    *reinterpret_cast<uint4*>(&Bs[br][bc])     = *reinterpret_cast<const uint4*>(Bp + k0);
    __syncthreads();
    bf16x8 af[4], bfr[2];
#pragma unroll
    for (int mt = 0; mt < 4; ++mt) af[mt]  = ld8(&As[wm + mt * 16 + l15][q4 * 8]);
#pragma unroll
    for (int nt = 0; nt < 2; ++nt) bfr[nt] = ld8(&Bs[wn + nt * 16 + l15][q4 * 8]);
#pragma unroll
    for (int mt = 0; mt < 4; ++mt)
#pragma unroll
      for (int nt = 0; nt < 2; ++nt)
        acc[mt][nt] = __builtin_amdgcn_mfma_f32_16x16x32_bf16(af[mt], bfr[nt], acc[mt][nt], 0, 0, 0);
    __syncthreads();
  }
#pragma unroll
  for (int mt = 0; mt < 4; ++mt)
#pragma unroll
    for (int nt = 0; nt < 2; ++nt)
#pragma unroll
      for (int r = 0; r < 4; ++r) {
        const int gm = m0 + wm + mt * 16 + q4 * 4 + r;   // C/D: row = quad*4+reg
        const int gn = n0 + wn + nt * 16 + l15;          //      col = lane&15
        const OutT ov = cvt_out<OutT>(acc[mt][nt][r] * scale);
        if (C2 == nullptr) {
          C[(size_t)gm * Nn + gn] = ov;
        } else if (gn < HD) {
          C[(size_t)gm * HD + gn] = ov;                              // K: (B*SEQ, 64)
        } else {
          C2[((size_t)(gm >> 11) * HD + (gn - HD)) * SEQ + (gm & 2047)] = ov;  // V^T
        }
      }
}

// ---------------- flash attention: 64 q-rows/block, 32-key tiles ----------------
__global__ __launch_bounds__(256) void flash_attn(
    const bf16_t* __restrict__ q,     // (B, SEQ, DM), head h at cols h*64..
    const bf16_t* __restrict__ kk,    // (B, SEQ, HD)
    const bf16_t* __restrict__ vT,    // (B, HD, SEQ)
    const float*  __restrict__ bias,  // (NHEAD, SEQ, SEQ)
    const int*    __restrict__ mask,  // (B, SEQ)
    bf16_t* __restrict__ aout)        // (B, SEQ, DM)
{
  const int b = blockIdx.y & 1, h = blockIdx.y >> 1;  // b fastest: bias tile L2 reuse
  const int i0 = blockIdx.x * 64;
  const int t = threadIdx.x, lane = t & 63, w = t >> 6;
  const int l15 = lane & 15, q4 = lane >> 4;

  __shared__ alignas(16) bf16_t Qs[64][72];
  __shared__ alignas(16) bf16_t Ks[32][72];
  __shared__ alignas(16) bf16_t Vs[64][40];
  __shared__ alignas(16) bf16_t Ps[4][16][40];

  {
    const int r = t >> 2, c = (t & 3) * 16;
    const bf16_t* src = &q[((size_t)b * SEQ + i0 + r) * DM + h * HD + c];
    *reinterpret_cast<uint4*>(&Qs[r][c])     = *reinterpret_cast<const uint4*>(src);
    *reinterpret_cast<uint4*>(&Qs[r][c + 8]) = *reinterpret_cast<const uint4*>(src + 8);
  }
  __syncthreads();
  const bf16x8 aq0 = ld8(&Qs[w * 16 + l15][q4 * 8]);        // A[m=lane&15][k=quad*8+j]
  const bf16x8 aq1 = ld8(&Qs[w * 16 + l15][32 + q4 * 8]);

  f32x4 o[4] = {};
  float m_run[4], l_run[4];
#pragma unroll
  for (int r = 0; r < 4; ++r) { m_run[r] = -1e30f; l_run[r] = 0.0f; }

  const float* bias_h = bias + (size_t)h * SEQ * SEQ;

  for (int j0 = 0; j0 < SEQ; j0 += 32) {
    {
      const int r = t >> 3, c = (t & 7) * 8;
      *reinterpret_cast<uint4*>(&Ks[r][c]) =
          *reinterpret_cast<const uint4*>(&kk[((size_t)b * SEQ + j0 + r) * HD + c]);
    }
    {
      const int r = t >> 2, c = (t & 3) * 8;
      *reinterpret_cast<uint4*>(&Vs[r][c]) =
          *reinterpret_cast<const uint4*>(&vT[((size_t)b * HD + r) * SEQ + j0 + c]);
    }
    __syncthreads();

    // S tile: 16 q-rows x 32 keys (2 j-subtiles x 2 dh-halves)
    f32x4 s[2];
#pragma unroll
    for (int jn = 0; jn < 2; ++jn) {
      bf16x8 bk0 = ld8(&Ks[jn * 16 + l15][q4 * 8]);         // B[k=quad*8+j][n=lane&15]
      bf16x8 bk1 = ld8(&Ks[jn * 16 + l15][32 + q4 * 8]);
      f32x4 z = {0.f, 0.f, 0.f, 0.f};
      z = __builtin_amdgcn_mfma_f32_16x16x32_bf16(aq0, bk0, z, 0, 0, 0);
      z = __builtin_amdgcn_mfma_f32_16x16x32_bf16(aq1, bk1, z, 0, 0, 0);
      s[jn] = z;
    }

    const int mk0 = mask[b * SEQ + j0 + l15];
    const int mk1 = mask[b * SEQ + j0 + 16 + l15];
#pragma unroll
    for (int jn = 0; jn < 2; ++jn) {
      const int gj = j0 + jn * 16 + l15;
      const int mkv = jn ? mk1 : mk0;
#pragma unroll
      for (int r = 0; r < 4; ++r) {
        const int gi = i0 + w * 16 + q4 * 4 + r;
        const float sv = s[jn][r] + bias_h[(size_t)gi * SEQ + gj];
        s[jn][r] = mkv ? sv : -1e30f;
      }
    }

    float mnew[4], alpha[4];
#pragma unroll
    for (int r = 0; r < 4; ++r) {
      float mx = fmaxf(s[0][r], s[1][r]);
#pragma unroll
      for (int off = 1; off < 16; off <<= 1) mx = fmaxf(mx, __shfl_xor(mx, off, 64));
      mnew[r]  = fmaxf(m_run[r], mx);
      alpha[r] = __expf(m_run[r] - mnew[r]);   // first iter: exp(-1e30)=0
      m_run[r] = mnew[r];
    }
    float p[2][4];
#pragma unroll
    for (int jn = 0; jn < 2; ++jn)
#pragma unroll
      for (int r = 0; r < 4; ++r) p[jn][r] = __expf(s[jn][r] - mnew[r]);
#pragma unroll
    for (int r = 0; r < 4; ++r) {
      float su = p[0][r] + p[1][r];
#pragma unroll
      for (int off = 1; off < 16; off <<= 1) su += __shfl_xor(su, off, 64);
      l_run[r] = l_run[r] * alpha[r] + su;
    }
#pragma unroll
    for (int nt = 0; nt < 4; ++nt)
#pragma unroll
      for (int r = 0; r < 4; ++r) o[nt][r] *= alpha[r];

    // P: C-layout -> LDS -> A-layout (per-wave buffer; same-wave DS ops are in-order)
#pragma unroll
    for (int jn = 0; jn < 2; ++jn)
#pragma unroll
      for (int r = 0; r < 4; ++r)
        Ps[w][q4 * 4 + r][jn * 16 + l15] = (bf16_t)p[jn][r];
    const bf16x8 pf = ld8(&Ps[w][l15][q4 * 8]);
#pragma unroll
    for (int nt = 0; nt < 4; ++nt) {
      bf16x8 bv = ld8(&Vs[nt * 16 + l15][q4 * 8]);  // B[k=j][n=dh] from V^T tile
      o[nt] = __builtin_amdgcn_mfma_f32_16x16x32_bf16(pf, bv, o[nt], 0, 0, 0);
    }
    __syncthreads();
  }

#pragma unroll
  for (int nt = 0; nt < 4; ++nt)
#pragma unroll
    for (int r = 0; r < 4; ++r) {
      const int gi = i0 + w * 16 + q4 * 4 + r;
      aout[((size_t)b * SEQ + gi) * DM + h * HD + nt * 16 + l15] =
          (bf16_t)(o[nt][r] / l_run[r]);
    }
}

extern "C" void kernel_launch(void* const* d_in, const int* in_sizes, int n_in,
                              void* d_out, int out_size, void* d_ws, size_t ws_size,
                              hipStream_t stream) {
  const float* x         = (const float*)d_in[0];
  const float* attn_bias = (const float*)d_in[1];
  const float* ln_w      = (const float*)d_in[2];
  const float* ln_b      = (const float*)d_in[3];
  const float* wq        = (const float*)d_in[4];
  const float* wkv       = (const float*)d_in[5];
  const float* wo        = (const float*)d_in[6];
  const int*   mask      = (const int*)d_in[7];
  float* out = (float*)d_out;

  char* ws = (char*)d_ws;
  size_t off = 0;
  auto alloc = [&](size_t bytes) {
    char* p = ws + off;
    off += (bytes + 255) & ~(size_t)255;
    return p;
  };
  bf16_t* xbf  = (bf16_t*)alloc((size_t)BB * SEQ * DM * 2);
  bf16_t* xn   = (bf16_t*)alloc((size_t)BB * SEQ * DM * 2);
  bf16_t* wqT  = (bf16_t*)alloc((size_t)DM * DM * 2);
  bf16_t* wkvT = (bf16_t*)alloc((size_t)2 * HD * DM * 2);
  bf16_t* woT  = (bf16_t*)alloc((size_t)DM * DM * 2);
  bf16_t* qb   = (bf16_t*)alloc((size_t)BB * SEQ * DM * 2);
  bf16_t* kkb  = (bf16_t*)alloc((size_t)BB * SEQ * HD * 2);
  bf16_t* vTb  = (bf16_t*)alloc((size_t)BB * HD * SEQ * 2);
  bf16_t* aout = (bf16_t*)alloc((size_t)BB * SEQ * DM * 2);

  transpose_cast<<<dim3(DM / 32, DM / 32), 256, 0, stream>>>(wq, wqT, DM, DM);
  transpose_cast<<<dim3(128 / 32, DM / 32), 256, 0, stream>>>(wkv, wkvT, DM, 128);
  transpose_cast<<<dim3(DM / 32, DM / 32), 256, 0, stream>>>(wo, woT, DM, DM);
  row_prep<<<BB * SEQ, 256, 0, stream>>>(x, ln_w, ln_b, xbf, xn);
  // q = xn @ wq, scaled by DH^-0.5
  gemm_bt<bf16_t><<<dim3(32, 16), 256, 0, stream>>>(xn, wqT, qb, (bf16_t*)nullptr,
                                                    BB * SEQ, DM, DM, 0.125f);
  // kv = x @ wkv, split into K (B,SEQ,64) and V^T (B,64,SEQ)
  gemm_bt<bf16_t><<<dim3(32, 2), 256, 0, stream>>>(xbf, wkvT, kkb, vTb,
                                                   BB * SEQ, 128, DM, 1.0f);
  flash_attn<<<dim3(SEQ / 64, BB * NHEAD), 256, 0, stream>>>(qb, kkb, vTb, attn_bias,
                                                             mask, aout);
  // out = aout @ wo (fp32 output)
  gemm_bt<float><<<dim3(32, 16), 256, 0, stream>>>(aout, woT, out, (float*)nullptr,
                                                   BB * SEQ, DM, DM, 1.0f);
}

// Round 2
// 525.924 us; speedup vs baseline: 1.0970x; 1.0970x over previous
//
#include <hip/hip_runtime.h>
#include <hip/hip_bf16.h>

typedef __bf16 bf16_t;
typedef __bf16 bf16x4 __attribute__((ext_vector_type(4)));
typedef __bf16 bf16x8 __attribute__((ext_vector_type(8)));
typedef float f32x4 __attribute__((ext_vector_type(4)));

static constexpr int BB    = 2;
static constexpr int SEQ   = 2048;
static constexpr int DM    = 1024;   // D == INNER
static constexpr int NHEAD = 16;
static constexpr int HD    = 64;
static constexpr float L2E = 1.4426950408889634f;

__device__ __forceinline__ bf16x8 ld8(const bf16_t* p) {
  return *reinterpret_cast<const bf16x8*>(p);
}

// async global->LDS, 16B per lane. LDS dest is wave-uniform base + lane*16.
__device__ __forceinline__ void gl_lds16(const bf16_t* g, bf16_t* l) {
  __builtin_amdgcn_global_load_lds(
      (const __attribute__((address_space(1))) void*)g,
      (__attribute__((address_space(3))) void*)l, 16, 0, 0);
}

template <typename T> __device__ __forceinline__ T cvt_out(float v);
template <> __device__ __forceinline__ float  cvt_out<float >(float v) { return v; }
template <> __device__ __forceinline__ bf16_t cvt_out<bf16_t>(float v) { return (bf16_t)v; }

// ---------------- transpose + cast: in (R,C) fp32 -> out (C,R) bf16 ----------------
__global__ __launch_bounds__(256) void transpose_cast(const float* __restrict__ in,
                                                      bf16_t* __restrict__ out,
                                                      int R, int C) {
  __shared__ float tile[32][33];
  const int c0 = blockIdx.x * 32, r0 = blockIdx.y * 32;
  const int tx = threadIdx.x & 31, ty = threadIdx.x >> 5;
#pragma unroll
  for (int y = ty; y < 32; y += 8)
    tile[y][tx] = in[(size_t)(r0 + y) * C + (c0 + tx)];
  __syncthreads();
#pragma unroll
  for (int y = ty; y < 32; y += 8)
    out[(size_t)(c0 + y) * R + (r0 + tx)] = (bf16_t)tile[tx][y];
}

// -------- LayerNorm row kernel: emits x(bf16), xn(bf16), maskA(float addend) --------
__global__ __launch_bounds__(256) void row_prep(const float* __restrict__ x,
    const float* __restrict__ ln_w, const float* __restrict__ ln_b,
    const int* __restrict__ mask,
    bf16_t* __restrict__ xbf, bf16_t* __restrict__ xn, float* __restrict__ maskA) {
  const int row = blockIdx.x, t = threadIdx.x;
  __shared__ float red[8];
  const float4 xv = *reinterpret_cast<const float4*>(&x[(size_t)row * DM + t * 4]);
  float s  = xv.x + xv.y + xv.z + xv.w;
  float s2 = xv.x * xv.x + xv.y * xv.y + xv.z * xv.z + xv.w * xv.w;
#pragma unroll
  for (int off = 32; off >= 1; off >>= 1) {
    s  += __shfl_xor(s,  off, 64);
    s2 += __shfl_xor(s2, off, 64);
  }
  if ((t & 63) == 0) { red[t >> 6] = s; red[4 + (t >> 6)] = s2; }
  __syncthreads();
  s  = red[0] + red[1] + red[2] + red[3];
  s2 = red[4] + red[5] + red[6] + red[7];
  const float mu   = s * (1.0f / DM);
  const float var  = s2 * (1.0f / DM) - mu * mu;
  const float rstd = rsqrtf(var + 1e-5f);
  const float4 wv = *reinterpret_cast<const float4*>(&ln_w[t * 4]);
  const float4 bv = *reinterpret_cast<const float4*>(&ln_b[t * 4]);
  union { bf16_t h[4]; uint2 u; } p0, p1;
  p0.h[0] = (bf16_t)xv.x; p0.h[1] = (bf16_t)xv.y;
  p0.h[2] = (bf16_t)xv.z; p0.h[3] = (bf16_t)xv.w;
  p1.h[0] = (bf16_t)((xv.x - mu) * rstd * wv.x + bv.x);
  p1.h[1] = (bf16_t)((xv.y - mu) * rstd * wv.y + bv.y);
  p1.h[2] = (bf16_t)((xv.z - mu) * rstd * wv.z + bv.z);
  p1.h[3] = (bf16_t)((xv.w - mu) * rstd * wv.w + bv.w);
  *reinterpret_cast<uint2*>(&xbf[(size_t)row * DM + t * 4]) = p0.u;
  *reinterpret_cast<uint2*>(&xn [(size_t)row * DM + t * 4]) = p1.u;
  if (t == 0) maskA[row] = mask[row] ? 0.0f : -1e30f;
}

// ---- m97-style bf16 MFMA GEMM: C(M,Nn) = A(M,K)*Bt(Nn,K)^T, 128x64 tile, BK=32 ----
// global_load_lds width-16 staging, unpadded LDS. C2!=null: kv-split epilogue.
template <typename OutT>
__global__ __launch_bounds__(256) void gemm_lds(const bf16_t* __restrict__ A,
    const bf16_t* __restrict__ Bt, OutT* __restrict__ C, OutT* __restrict__ C2,
    int M, int Nn, int K, float scale) {
  __shared__ alignas(16) bf16_t As[128 * 32];
  __shared__ alignas(16) bf16_t Bs[64 * 32];
  const int m0 = blockIdx.x * 128, n0 = blockIdx.y * 64;
  const int t = threadIdx.x, lane = t & 63, w = t >> 6;
  const int wm = (w & 1) * 64, wn = (w >> 1) * 32;
  const int l15 = lane & 15, q4 = lane >> 4;
  f32x4 acc[4][2] = {};
  const int sr = lane >> 2, sc = (lane & 3) * 8;   // lane i -> row i/4, col (i&3)*8
  const bf16_t* Ap0 = A  + (size_t)(m0 + w * 32 + sr) * K + sc;
  const bf16_t* Ap1 = Ap0 + (size_t)16 * K;
  const bf16_t* Bp  = Bt + (size_t)(n0 + w * 16 + sr) * K + sc;
  bf16_t* AsL0 = &As[(w * 32) * 32];
  bf16_t* AsL1 = &As[(w * 32 + 16) * 32];
  bf16_t* BsL  = &Bs[(w * 16) * 32];
  for (int k0 = 0; k0 < K; k0 += 32) {
    gl_lds16(Ap0 + k0, AsL0);
    gl_lds16(Ap1 + k0, AsL1);
    gl_lds16(Bp  + k0, BsL);
    __syncthreads();
    bf16x8 af[4], bfr[2];
#pragma unroll
    for (int mt = 0; mt < 4; ++mt) af[mt]  = ld8(&As[(wm + mt * 16 + l15) * 32 + q4 * 8]);
#pragma unroll
    for (int nt = 0; nt < 2; ++nt) bfr[nt] = ld8(&Bs[(wn + nt * 16 + l15) * 32 + q4 * 8]);
#pragma unroll
    for (int mt = 0; mt < 4; ++mt)
#pragma unroll
      for (int nt = 0; nt < 2; ++nt)
        acc[mt][nt] = __builtin_amdgcn_mfma_f32_16x16x32_bf16(af[mt], bfr[nt], acc[mt][nt], 0, 0, 0);
    __syncthreads();
  }
#pragma unroll
  for (int mt = 0; mt < 4; ++mt)
#pragma unroll
    for (int nt = 0; nt < 2; ++nt)
#pragma unroll
      for (int r = 0; r < 4; ++r) {
        const int gm = m0 + wm + mt * 16 + q4 * 4 + r;   // C/D: row = quad*4+reg
        const int gn = n0 + wn + nt * 16 + l15;          //      col = lane&15
        const OutT ov = cvt_out<OutT>(acc[mt][nt][r] * scale);
        if (C2 == nullptr) {
          C[(size_t)gm * Nn + gn] = ov;
        } else if (gn < HD) {
          C[(size_t)gm * HD + gn] = ov;                              // K: (B*SEQ, 64)
        } else {
          C2[((size_t)(gm >> 11) * HD + (gn - HD)) * SEQ + (gm & 2047)] = ov;  // V^T
        }
      }
}

// ------- flash attention, S^T orientation: 64 q-rows/block, 64-key tiles -------
// S^T tile per wave: keys=M (64, 4 subtiles), queries=N (16 = lane&15).
// Per-lane softmax state is a single scalar (its l15 query).
__global__ __launch_bounds__(256) void flash_attn(
    const bf16_t* __restrict__ q,     // (B, SEQ, DM), head h at cols h*64..
    const bf16_t* __restrict__ kk,    // (B, SEQ, HD)
    const bf16_t* __restrict__ vT,    // (B, HD, SEQ)
    const float*  __restrict__ bias,  // (NHEAD, SEQ, SEQ)
    const float*  __restrict__ maskA, // (B, SEQ): 0 or -1e30
    bf16_t* __restrict__ aout)        // (B, SEQ, DM)
{
  const int b = blockIdx.y & 1, h = blockIdx.y >> 1;  // b fastest: bias tile L2 reuse
  const int i0 = blockIdx.x * 64;
  const int t = threadIdx.x, lane = t & 63, w = t >> 6;
  const int l15 = lane & 15, q4 = lane >> 4;

  __shared__ alignas(16) bf16_t Qs[64][72];
  __shared__ alignas(16) bf16_t Ks[64][72];   // [key][dh]
  __shared__ alignas(16) bf16_t Vs[64][72];   // [dh][key]
  __shared__ alignas(16) bf16_t Pt[4][16][72];// per wave: [query][key]

  const int sr = t >> 2, sc = (t & 3) * 16;
  {
    const bf16_t* src = &q[((size_t)b * SEQ + i0 + sr) * DM + h * HD + sc];
    *reinterpret_cast<uint4*>(&Qs[sr][sc])     = *reinterpret_cast<const uint4*>(src);
    *reinterpret_cast<uint4*>(&Qs[sr][sc + 8]) = *reinterpret_cast<const uint4*>(src + 8);
  }
  __syncthreads();
  // Q as B-operand: B[k=dh][n=query]
  const bf16x8 bq0 = ld8(&Qs[w * 16 + l15][q4 * 8]);
  const bf16x8 bq1 = ld8(&Qs[w * 16 + l15][32 + q4 * 8]);

  f32x4 o[4] = {};
  float m_run = -1e30f, l_run = 0.0f;

  const float* bias_p = bias + (size_t)h * SEQ * SEQ
                      + (size_t)(i0 + w * 16 + l15) * SEQ + q4 * 4;
  const float* mask_p = maskA + b * SEQ + q4 * 4;
  const bf16_t* kp = &kk[((size_t)b * SEQ + sr) * HD + sc];
  const bf16_t* vp = &vT[((size_t)b * HD + sr) * SEQ + sc];

  for (int j0 = 0; j0 < SEQ; j0 += 64) {
    {
      const bf16_t* ks = kp + (size_t)j0 * HD;
      *reinterpret_cast<uint4*>(&Ks[sr][sc])     = *reinterpret_cast<const uint4*>(ks);
      *reinterpret_cast<uint4*>(&Ks[sr][sc + 8]) = *reinterpret_cast<const uint4*>(ks + 8);
      const bf16_t* vs = vp + j0;
      *reinterpret_cast<uint4*>(&Vs[sr][sc])     = *reinterpret_cast<const uint4*>(vs);
      *reinterpret_cast<uint4*>(&Vs[sr][sc + 8]) = *reinterpret_cast<const uint4*>(vs + 8);
    }
    // bias + mask loads (independent of LDS; overlap with barrier/MFMA)
    f32x4 bv[4], mv[4];
#pragma unroll
    for (int mt = 0; mt < 4; ++mt) {
      bv[mt] = *reinterpret_cast<const f32x4*>(bias_p + j0 + mt * 16);
      mv[mt] = *reinterpret_cast<const f32x4*>(mask_p + j0 + mt * 16);
    }
    __syncthreads();

    // S^T: D[m=key][n=query] = K·Q^T  (4 key-subtiles x 2 dh-halves)
    f32x4 s[4];
#pragma unroll
    for (int mt = 0; mt < 4; ++mt) {
      const bf16x8 a0 = ld8(&Ks[mt * 16 + l15][q4 * 8]);
      const bf16x8 a1 = ld8(&Ks[mt * 16 + l15][32 + q4 * 8]);
      f32x4 z = {0.f, 0.f, 0.f, 0.f};
      z = __builtin_amdgcn_mfma_f32_16x16x32_bf16(a0, bq0, z, 0, 0, 0);
      z = __builtin_amdgcn_mfma_f32_16x16x32_bf16(a1, bq1, z, 0, 0, 0);
      s[mt] = z;
    }

    // t = s + bias + maskadd; row (=query) max over this lane's 16 keys
    float mx = -1e30f;
#pragma unroll
    for (int mt = 0; mt < 4; ++mt)
#pragma unroll
      for (int r = 0; r < 4; ++r) {
        s[mt][r] = s[mt][r] + bv[mt][r] + mv[mt][r];
        mx = fmaxf(mx, s[mt][r]);
      }
    mx = fmaxf(mx, __shfl_xor(mx, 16, 64));
    mx = fmaxf(mx, __shfl_xor(mx, 32, 64));
    const float mnew  = fmaxf(m_run, mx);
    const float alpha = __builtin_amdgcn_exp2f((m_run - mnew) * L2E);
    const float cc    = -mnew * L2E;
    m_run = mnew;

    float su = 0.0f;
#pragma unroll
    for (int mt = 0; mt < 4; ++mt)
#pragma unroll
      for (int r = 0; r < 4; ++r) {
        s[mt][r] = __builtin_amdgcn_exp2f(__builtin_fmaf(s[mt][r], L2E, cc));
        su += s[mt][r];
      }
    su += __shfl_xor(su, 16, 64);
    su += __shfl_xor(su, 32, 64);
    l_run = l_run * alpha + su;

    // P^T -> Pt[query][key] (4 adjacent keys per b64 write)
#pragma unroll
    for (int mt = 0; mt < 4; ++mt) {
      bf16x4 pk = {(bf16_t)s[mt][0], (bf16_t)s[mt][1], (bf16_t)s[mt][2], (bf16_t)s[mt][3]};
      *reinterpret_cast<bf16x4*>(&Pt[w][l15][mt * 16 + q4 * 4]) = pk;
    }

    // rescale O by alpha of query q4*4+r (broadcast from lane holding that query)
#pragma unroll
    for (int r = 0; r < 4; ++r) {
      const float a_r = __shfl(alpha, (q4 << 2) + r, 64);
      o[0][r] *= a_r; o[1][r] *= a_r; o[2][r] *= a_r; o[3][r] *= a_r;
    }

    // O[m=query][n=dh] += P·V  (A from Pt, B from Vs=V^T)
#pragma unroll
    for (int ks = 0; ks < 2; ++ks) {
      const bf16x8 pf = ld8(&Pt[w][l15][ks * 32 + q4 * 8]);
#pragma unroll
      for (int nt = 0; nt < 4; ++nt) {
        const bf16x8 vv = ld8(&Vs[nt * 16 + l15][ks * 32 + q4 * 8]);
        o[nt] = __builtin_amdgcn_mfma_f32_16x16x32_bf16(pf, vv, o[nt], 0, 0, 0);
      }
    }
    __syncthreads();
  }

#pragma unroll
  for (int r = 0; r < 4; ++r) {
    const float linv = 1.0f / __shfl(l_run, (q4 << 2) + r, 64);
    const int gi = i0 + w * 16 + q4 * 4 + r;
    bf16_t* dst = &aout[((size_t)b * SEQ + gi) * DM + h * HD];
#pragma unroll
    for (int nt = 0; nt < 4; ++nt)
      dst[nt * 16 + l15] = (bf16_t)(o[nt][r] * linv);
  }
}

extern "C" void kernel_launch(void* const* d_in, const int* in_sizes, int n_in,
                              void* d_out, int out_size, void* d_ws, size_t ws_size,
                              hipStream_t stream) {
  const float* x         = (const float*)d_in[0];
  const float* attn_bias = (const float*)d_in[1];
  const float* ln_w      = (const float*)d_in[2];
  const float* ln_b      = (const float*)d_in[3];
  const float* wq        = (const float*)d_in[4];
  const float* wkv       = (const float*)d_in[5];
  const float* wo        = (const float*)d_in[6];
  const int*   mask      = (const int*)d_in[7];
  float* out = (float*)d_out;

  char* ws = (char*)d_ws;
  size_t off = 0;
  auto alloc = [&](size_t bytes) {
    char* p = ws + off;
    off += (bytes + 255) & ~(size_t)255;
    return p;
  };
  bf16_t* xbf   = (bf16_t*)alloc((size_t)BB * SEQ * DM * 2);
  bf16_t* xn    = (bf16_t*)alloc((size_t)BB * SEQ * DM * 2);
  bf16_t* wqT   = (bf16_t*)alloc((size_t)DM * DM * 2);
  bf16_t* wkvT  = (bf16_t*)alloc((size_t)2 * HD * DM * 2);
  bf16_t* woT   = (bf16_t*)alloc((size_t)DM * DM * 2);
  bf16_t* qb    = (bf16_t*)alloc((size_t)BB * SEQ * DM * 2);
  bf16_t* kkb   = (bf16_t*)alloc((size_t)BB * SEQ * HD * 2);
  bf16_t* vTb   = (bf16_t*)alloc((size_t)BB * HD * SEQ * 2);
  bf16_t* aoutb = (bf16_t*)alloc((size_t)BB * SEQ * DM * 2);
  float*  maskA = (float*)alloc((size_t)BB * SEQ * 4);

  transpose_cast<<<dim3(DM / 32, DM / 32), 256, 0, stream>>>(wq, wqT, DM, DM);
  transpose_cast<<<dim3(128 / 32, DM / 32), 256, 0, stream>>>(wkv, wkvT, DM, 128);
  transpose_cast<<<dim3(DM / 32, DM / 32), 256, 0, stream>>>(wo, woT, DM, DM);
  row_prep<<<BB * SEQ, 256, 0, stream>>>(x, ln_w, ln_b, mask, xbf, xn, maskA);
  // q = xn @ wq, scaled by DH^-0.5
  gemm_lds<bf16_t><<<dim3(32, 16), 256, 0, stream>>>(xn, wqT, qb, (bf16_t*)nullptr,
                                                     BB * SEQ, DM, DM, 0.125f);
  // kv = x @ wkv -> K (B,SEQ,64) and V^T (B,64,SEQ)
  gemm_lds<bf16_t><<<dim3(32, 2), 256, 0, stream>>>(xbf, wkvT, kkb, vTb,
                                                    BB * SEQ, 128, DM, 1.0f);
  flash_attn<<<dim3(SEQ / 64, BB * NHEAD), 256, 0, stream>>>(qb, kkb, vTb, attn_bias,
                                                             maskA, aoutb);
  // out = aout @ wo (fp32 output)
  gemm_lds<float><<<dim3(32, 16), 256, 0, stream>>>(aoutb, woT, out, (float*)nullptr,
                                                    BB * SEQ, DM, DM, 1.0f);
}

// Round 3
// 512.211 us; speedup vs baseline: 1.1264x; 1.0268x over previous
//
#include <hip/hip_runtime.h>
#include <hip/hip_bf16.h>

typedef __bf16 bf16_t;
typedef __bf16 bf16x4 __attribute__((ext_vector_type(4)));
typedef __bf16 bf16x8 __attribute__((ext_vector_type(8)));
typedef float f32x4 __attribute__((ext_vector_type(4)));

static constexpr int BB    = 2;
static constexpr int SEQ   = 2048;
static constexpr int DM    = 1024;   // D == INNER
static constexpr int NHEAD = 16;
static constexpr int HD    = 64;
static constexpr float L2E = 1.4426950408889634f;

__device__ __forceinline__ bf16x8 ld8(const bf16_t* p) {
  return *reinterpret_cast<const bf16x8*>(p);
}

// async global->LDS, 16B per lane. LDS dest is wave-uniform base + lane*16.
__device__ __forceinline__ void gl_lds16(const bf16_t* g, bf16_t* l) {
  __builtin_amdgcn_global_load_lds(
      (const __attribute__((address_space(1))) void*)g,
      (__attribute__((address_space(3))) void*)l, 16, 0, 0);
}

__device__ __forceinline__ uint2 shfl2(uint2 v, int src) {
  uint2 r;
  r.x = (unsigned)__shfl((int)v.x, src, 64);
  r.y = (unsigned)__shfl((int)v.y, src, 64);
  return r;
}

template <typename T> __device__ __forceinline__ T cvt_out(float v);
template <> __device__ __forceinline__ float  cvt_out<float >(float v) { return v; }
template <> __device__ __forceinline__ bf16_t cvt_out<bf16_t>(float v) { return (bf16_t)v; }

// ---------------- transpose + cast: in (R,C) fp32 -> out (C,R) bf16 ----------------
__global__ __launch_bounds__(256) void transpose_cast(const float* __restrict__ in,
                                                      bf16_t* __restrict__ out,
                                                      int R, int C) {
  __shared__ float tile[32][33];
  const int c0 = blockIdx.x * 32, r0 = blockIdx.y * 32;
  const int tx = threadIdx.x & 31, ty = threadIdx.x >> 5;
#pragma unroll
  for (int y = ty; y < 32; y += 8)
    tile[y][tx] = in[(size_t)(r0 + y) * C + (c0 + tx)];
  __syncthreads();
#pragma unroll
  for (int y = ty; y < 32; y += 8)
    out[(size_t)(c0 + y) * R + (r0 + tx)] = (bf16_t)tile[tx][y];
}

// -------- LayerNorm row kernel: emits x(bf16), xn(bf16), maskA(float addend) --------
__global__ __launch_bounds__(256) void row_prep(const float* __restrict__ x,
    const float* __restrict__ ln_w, const float* __restrict__ ln_b,
    const int* __restrict__ mask,
    bf16_t* __restrict__ xbf, bf16_t* __restrict__ xn, float* __restrict__ maskA) {
  const int row = blockIdx.x, t = threadIdx.x;
  __shared__ float red[8];
  const float4 xv = *reinterpret_cast<const float4*>(&x[(size_t)row * DM + t * 4]);
  float s  = xv.x + xv.y + xv.z + xv.w;
  float s2 = xv.x * xv.x + xv.y * xv.y + xv.z * xv.z + xv.w * xv.w;
#pragma unroll
  for (int off = 32; off >= 1; off >>= 1) {
    s  += __shfl_xor(s,  off, 64);
    s2 += __shfl_xor(s2, off, 64);
  }
  if ((t & 63) == 0) { red[t >> 6] = s; red[4 + (t >> 6)] = s2; }
  __syncthreads();
  s  = red[0] + red[1] + red[2] + red[3];
  s2 = red[4] + red[5] + red[6] + red[7];
  const float mu   = s * (1.0f / DM);
  const float var  = s2 * (1.0f / DM) - mu * mu;
  const float rstd = rsqrtf(var + 1e-5f);
  const float4 wv = *reinterpret_cast<const float4*>(&ln_w[t * 4]);
  const float4 bv = *reinterpret_cast<const float4*>(&ln_b[t * 4]);
  union { bf16_t h[4]; uint2 u; } p0, p1;
  p0.h[0] = (bf16_t)xv.x; p0.h[1] = (bf16_t)xv.y;
  p0.h[2] = (bf16_t)xv.z; p0.h[3] = (bf16_t)xv.w;
  p1.h[0] = (bf16_t)((xv.x - mu) * rstd * wv.x + bv.x);
  p1.h[1] = (bf16_t)((xv.y - mu) * rstd * wv.y + bv.y);
  p1.h[2] = (bf16_t)((xv.z - mu) * rstd * wv.z + bv.z);
  p1.h[3] = (bf16_t)((xv.w - mu) * rstd * wv.w + bv.w);
  *reinterpret_cast<uint2*>(&xbf[(size_t)row * DM + t * 4]) = p0.u;
  *reinterpret_cast<uint2*>(&xn [(size_t)row * DM + t * 4]) = p1.u;
  if (t == 0) maskA[row] = mask[row] ? 0.0f : -1e30f;
}

// ---- m97-style 128x128 bf16 MFMA GEMM: C(M,Nn) = A(M,K)*Bt(Nn,K)^T, BK=32 ----
template <typename OutT>
__global__ __launch_bounds__(256) void gemm128(const bf16_t* __restrict__ A,
    const bf16_t* __restrict__ Bt, OutT* __restrict__ C,
    int M, int Nn, int K, float scale) {
  __shared__ alignas(16) bf16_t As[128 * 32];
  __shared__ alignas(16) bf16_t Bs[128 * 32];
  const int m0 = blockIdx.x * 128, n0 = blockIdx.y * 128;
  const int t = threadIdx.x, lane = t & 63, w = t >> 6;
  const int wm = (w & 1) * 64, wn = (w >> 1) * 64;
  const int l15 = lane & 15, q4 = lane >> 4;
  f32x4 acc[4][4] = {};
  const int sr = lane >> 2, sc = (lane & 3) * 8;   // 16 rows x 32 cols per issue
  const bf16_t* Ap0 = A  + (size_t)(m0 + w * 32 + sr) * K + sc;
  const bf16_t* Ap1 = Ap0 + (size_t)16 * K;
  const bf16_t* Bp0 = Bt + (size_t)(n0 + w * 32 + sr) * K + sc;
  const bf16_t* Bp1 = Bp0 + (size_t)16 * K;
  bf16_t* AsL0 = &As[(w * 32) * 32];
  bf16_t* AsL1 = &As[(w * 32 + 16) * 32];
  bf16_t* BsL0 = &Bs[(w * 32) * 32];
  bf16_t* BsL1 = &Bs[(w * 32 + 16) * 32];
  for (int k0 = 0; k0 < K; k0 += 32) {
    gl_lds16(Ap0 + k0, AsL0);
    gl_lds16(Ap1 + k0, AsL1);
    gl_lds16(Bp0 + k0, BsL0);
    gl_lds16(Bp1 + k0, BsL1);
    __syncthreads();
    bf16x8 af[4], bfr[4];
#pragma unroll
    for (int mt = 0; mt < 4; ++mt) af[mt]  = ld8(&As[(wm + mt * 16 + l15) * 32 + q4 * 8]);
#pragma unroll
    for (int nt = 0; nt < 4; ++nt) bfr[nt] = ld8(&Bs[(wn + nt * 16 + l15) * 32 + q4 * 8]);
#pragma unroll
    for (int mt = 0; mt < 4; ++mt)
#pragma unroll
      for (int nt = 0; nt < 4; ++nt)
        acc[mt][nt] = __builtin_amdgcn_mfma_f32_16x16x32_bf16(af[mt], bfr[nt], acc[mt][nt], 0, 0, 0);
    __syncthreads();
  }
#pragma unroll
  for (int mt = 0; mt < 4; ++mt)
#pragma unroll
    for (int nt = 0; nt < 4; ++nt)
#pragma unroll
      for (int r = 0; r < 4; ++r) {
        const int gm = m0 + wm + mt * 16 + q4 * 4 + r;
        const int gn = n0 + wn + nt * 16 + l15;
        C[(size_t)gm * Nn + gn] = cvt_out<OutT>(acc[mt][nt][r] * scale);
      }
}

// ---- 128x64 GEMM with kv-split epilogue: C=K (B*SEQ,64), C2=V^T (B,64,SEQ) ----
__global__ __launch_bounds__(256) void gemm_kv(const bf16_t* __restrict__ A,
    const bf16_t* __restrict__ Bt, bf16_t* __restrict__ C, bf16_t* __restrict__ C2,
    int M, int Nn, int K) {
  __shared__ alignas(16) bf16_t As[128 * 32];
  __shared__ alignas(16) bf16_t Bs[64 * 32];
  const int m0 = blockIdx.x * 128, n0 = blockIdx.y * 64;
  const int t = threadIdx.x, lane = t & 63, w = t >> 6;
  const int wm = (w & 1) * 64, wn = (w >> 1) * 32;
  const int l15 = lane & 15, q4 = lane >> 4;
  f32x4 acc[4][2] = {};
  const int sr = lane >> 2, sc = (lane & 3) * 8;
  const bf16_t* Ap0 = A  + (size_t)(m0 + w * 32 + sr) * K + sc;
  const bf16_t* Ap1 = Ap0 + (size_t)16 * K;
  const bf16_t* Bp  = Bt + (size_t)(n0 + w * 16 + sr) * K + sc;
  bf16_t* AsL0 = &As[(w * 32) * 32];
  bf16_t* AsL1 = &As[(w * 32 + 16) * 32];
  bf16_t* BsL  = &Bs[(w * 16) * 32];
  for (int k0 = 0; k0 < K; k0 += 32) {
    gl_lds16(Ap0 + k0, AsL0);
    gl_lds16(Ap1 + k0, AsL1);
    gl_lds16(Bp  + k0, BsL);
    __syncthreads();
    bf16x8 af[4], bfr[2];
#pragma unroll
    for (int mt = 0; mt < 4; ++mt) af[mt]  = ld8(&As[(wm + mt * 16 + l15) * 32 + q4 * 8]);
#pragma unroll
    for (int nt = 0; nt < 2; ++nt) bfr[nt] = ld8(&Bs[(wn + nt * 16 + l15) * 32 + q4 * 8]);
#pragma unroll
    for (int mt = 0; mt < 4; ++mt)
#pragma unroll
      for (int nt = 0; nt < 2; ++nt)
        acc[mt][nt] = __builtin_amdgcn_mfma_f32_16x16x32_bf16(af[mt], bfr[nt], acc[mt][nt], 0, 0, 0);
    __syncthreads();
  }
#pragma unroll
  for (int mt = 0; mt < 4; ++mt)
#pragma unroll
    for (int nt = 0; nt < 2; ++nt)
#pragma unroll
      for (int r = 0; r < 4; ++r) {
        const int gm = m0 + wm + mt * 16 + q4 * 4 + r;
        const int gn = n0 + wn + nt * 16 + l15;
        const bf16_t ov = (bf16_t)acc[mt][nt][r];
        if (gn < HD) C[(size_t)gm * HD + gn] = ov;
        else C2[((size_t)(gm >> 11) * HD + (gn - HD)) * SEQ + (gm & 2047)] = ov;
      }
}

// ------- flash attention v3: S^T orientation, 64 q-rows/block, 64-key tiles,
//         LDS double-buffered K/V (1 barrier/iter), shfl-based P transpose -------
__global__ __launch_bounds__(256, 4) void flash_attn(
    const bf16_t* __restrict__ q,     // (B, SEQ, DM), head h at cols h*64..
    const bf16_t* __restrict__ kk,    // (B, SEQ, HD)
    const bf16_t* __restrict__ vT,    // (B, HD, SEQ)
    const float*  __restrict__ bias,  // (NHEAD, SEQ, SEQ)
    const float*  __restrict__ maskA, // (B, SEQ): 0 or -1e30
    bf16_t* __restrict__ aout)        // (B, SEQ, DM)
{
  const int b = blockIdx.y & 1, h = blockIdx.y >> 1;  // b fastest: bias L2 reuse
  const int i0 = blockIdx.x * 64;
  const int t = threadIdx.x, lane = t & 63, w = t >> 6;
  const int l15 = lane & 15, q4 = lane >> 4;

  __shared__ alignas(16) bf16_t Ks[2][64][72];   // [key][dh]
  __shared__ alignas(16) bf16_t Vs[2][64][72];   // [dh][key]

  // Q fragments direct from global (B-operand: B[k=dh][n=query=l15])
  const bf16_t* qrow = &q[((size_t)b * SEQ + i0 + w * 16 + l15) * DM + h * HD];
  const bf16x8 bq0 = ld8(qrow + q4 * 8);
  const bf16x8 bq1 = ld8(qrow + 32 + q4 * 8);

  f32x4 o[4] = {};
  float m_run = -1e30f, l_run = 0.0f;

  const float* bias_p = bias + (size_t)h * SEQ * SEQ
                      + (size_t)(i0 + w * 16 + l15) * SEQ + q4 * 4;
  const float* mask_p = maskA + b * SEQ + q4 * 4;

  const int sr = t >> 2, sc = (t & 3) * 16;
  const bf16_t* kp = &kk[((size_t)b * SEQ + sr) * HD + sc];
  const bf16_t* vp = &vT[((size_t)b * HD + sr) * SEQ + sc];

  // prologue: tile 0 into buf 0, bias/mask iter-0 into regs
  uint4 kr0 = *reinterpret_cast<const uint4*>(kp);
  uint4 kr1 = *reinterpret_cast<const uint4*>(kp + 8);
  uint4 vr0 = *reinterpret_cast<const uint4*>(vp);
  uint4 vr1 = *reinterpret_cast<const uint4*>(vp + 8);
  f32x4 bv[4], mv[4];
#pragma unroll
  for (int mt = 0; mt < 4; ++mt) {
    bv[mt] = *reinterpret_cast<const f32x4*>(bias_p + mt * 16);
    mv[mt] = *reinterpret_cast<const f32x4*>(mask_p + mt * 16);
  }
  *reinterpret_cast<uint4*>(&Ks[0][sr][sc])     = kr0;
  *reinterpret_cast<uint4*>(&Ks[0][sr][sc + 8]) = kr1;
  *reinterpret_cast<uint4*>(&Vs[0][sr][sc])     = vr0;
  *reinterpret_cast<uint4*>(&Vs[0][sr][sc + 8]) = vr1;
  __syncthreads();

  for (int it = 0; it < SEQ / 64; ++it) {
    const int buf = it & 1;
    const int j1 = (it + 1) * 64;
    const bool more = (j1 < SEQ);
    if (more) {   // prefetch next K/V tile into regs (global, async)
      kr0 = *reinterpret_cast<const uint4*>(kp + (size_t)j1 * HD);
      kr1 = *reinterpret_cast<const uint4*>(kp + (size_t)j1 * HD + 8);
      vr0 = *reinterpret_cast<const uint4*>(vp + j1);
      vr1 = *reinterpret_cast<const uint4*>(vp + j1 + 8);
    }

    // S^T: D[m=key][n=query] = K·Q^T  (4 key-subtiles x 2 dh-halves)
    f32x4 s[4];
#pragma unroll
    for (int mt = 0; mt < 4; ++mt) {
      const bf16x8 a0 = ld8(&Ks[buf][mt * 16 + l15][q4 * 8]);
      const bf16x8 a1 = ld8(&Ks[buf][mt * 16 + l15][32 + q4 * 8]);
      f32x4 z = {0.f, 0.f, 0.f, 0.f};
      z = __builtin_amdgcn_mfma_f32_16x16x32_bf16(a0, bq0, z, 0, 0, 0);
      z = __builtin_amdgcn_mfma_f32_16x16x32_bf16(a1, bq1, z, 0, 0, 0);
      s[mt] = z;
    }

    // add bias + mask (consume current regs); per-query max over lane's 16 keys
    float mx = -1e30f;
#pragma unroll
    for (int mt = 0; mt < 4; ++mt)
#pragma unroll
      for (int r = 0; r < 4; ++r) {
        s[mt][r] = s[mt][r] + bv[mt][r] + mv[mt][r];
        mx = fmaxf(mx, s[mt][r]);
      }
    if (more) {   // prefetch next bias/mask into regs
#pragma unroll
      for (int mt = 0; mt < 4; ++mt) {
        bv[mt] = *reinterpret_cast<const f32x4*>(bias_p + j1 + mt * 16);
        mv[mt] = *reinterpret_cast<const f32x4*>(mask_p + j1 + mt * 16);
      }
    }
    mx = fmaxf(mx, __shfl_xor(mx, 16, 64));
    mx = fmaxf(mx, __shfl_xor(mx, 32, 64));
    const float mnew  = fmaxf(m_run, mx);
    const float alpha = __builtin_amdgcn_exp2f((m_run - mnew) * L2E);
    const float cc    = -mnew * L2E;
    m_run = mnew;

    float su = 0.0f;
#pragma unroll
    for (int mt = 0; mt < 4; ++mt)
#pragma unroll
      for (int r = 0; r < 4; ++r) {
        s[mt][r] = __builtin_amdgcn_exp2f(__builtin_fmaf(s[mt][r], L2E, cc));
        su += s[mt][r];
      }
    su += __shfl_xor(su, 16, 64);
    su += __shfl_xor(su, 32, 64);
    l_run = l_run * alpha + su;

    // rescale O by alpha of query q4*4+r (value uniform across quads)
#pragma unroll
    for (int r = 0; r < 4; ++r) {
      const float a_r = __shfl(alpha, q4 * 4 + r, 64);
      o[0][r] *= a_r; o[1][r] *= a_r; o[2][r] *= a_r; o[3][r] *= a_r;
    }

    // pack P^T (bf16x4 per key-subtile) and transpose to A-layout via shfl
    uint2 pk[4];
#pragma unroll
    for (int mt = 0; mt < 4; ++mt) {
      union { bf16_t hh[4]; uint2 u; } pu;
      pu.hh[0] = (bf16_t)s[mt][0]; pu.hh[1] = (bf16_t)s[mt][1];
      pu.hh[2] = (bf16_t)s[mt][2]; pu.hh[3] = (bf16_t)s[mt][3];
      pk[mt] = pu.u;
    }
    const int src0 = ((q4 & 1) << 5) + l15;   // lane holding keys [base..base+4)
    const int src1 = src0 + 16;               // lane holding keys [base+4..base+8)
    const bool hiSel = (q4 >> 1) != 0;        // which mt group this dest needs
#pragma unroll
    for (int ks = 0; ks < 2; ++ks) {
      const uint2 a0 = shfl2(pk[2 * ks],     src0);
      const uint2 a1 = shfl2(pk[2 * ks + 1], src0);
      const uint2 b0 = shfl2(pk[2 * ks],     src1);
      const uint2 b1 = shfl2(pk[2 * ks + 1], src1);
      union { unsigned u[4]; bf16x8 v; } pf;
      pf.u[0] = hiSel ? a1.x : a0.x; pf.u[1] = hiSel ? a1.y : a0.y;
      pf.u[2] = hiSel ? b1.x : b0.x; pf.u[3] = hiSel ? b1.y : b0.y;
#pragma unroll
      for (int nt = 0; nt < 4; ++nt) {
        const bf16x8 vv = ld8(&Vs[buf][nt * 16 + l15][ks * 32 + q4 * 8]);
        o[nt] = __builtin_amdgcn_mfma_f32_16x16x32_bf16(pf.v, vv, o[nt], 0, 0, 0);
      }
    }

    if (more) {   // store prefetched tile into the other buffer
      *reinterpret_cast<uint4*>(&Ks[buf ^ 1][sr][sc])     = kr0;
      *reinterpret_cast<uint4*>(&Ks[buf ^ 1][sr][sc + 8]) = kr1;
      *reinterpret_cast<uint4*>(&Vs[buf ^ 1][sr][sc])     = vr0;
      *reinterpret_cast<uint4*>(&Vs[buf ^ 1][sr][sc + 8]) = vr1;
    }
    __syncthreads();
  }

#pragma unroll
  for (int r = 0; r < 4; ++r) {
    const float linv = 1.0f / __shfl(l_run, q4 * 4 + r, 64);
    const int gi = i0 + w * 16 + q4 * 4 + r;
    bf16_t* dst = &aout[((size_t)b * SEQ + gi) * DM + h * HD];
#pragma unroll
    for (int nt = 0; nt < 4; ++nt)
      dst[nt * 16 + l15] = (bf16_t)(o[nt][r] * linv);
  }
}

extern "C" void kernel_launch(void* const* d_in, const int* in_sizes, int n_in,
                              void* d_out, int out_size, void* d_ws, size_t ws_size,
                              hipStream_t stream) {
  const float* x         = (const float*)d_in[0];
  const float* attn_bias = (const float*)d_in[1];
  const float* ln_w      = (const float*)d_in[2];
  const float* ln_b      = (const float*)d_in[3];
  const float* wq        = (const float*)d_in[4];
  const float* wkv       = (const float*)d_in[5];
  const float* wo        = (const float*)d_in[6];
  const int*   mask      = (const int*)d_in[7];
  float* out = (float*)d_out;

  char* ws = (char*)d_ws;
  size_t off = 0;
  auto alloc = [&](size_t bytes) {
    char* p = ws + off;
    off += (bytes + 255) & ~(size_t)255;
    return p;
  };
  bf16_t* xbf   = (bf16_t*)alloc((size_t)BB * SEQ * DM * 2);
  bf16_t* xn    = (bf16_t*)alloc((size_t)BB * SEQ * DM * 2);
  bf16_t* wqT   = (bf16_t*)alloc((size_t)DM * DM * 2);
  bf16_t* wkvT  = (bf16_t*)alloc((size_t)2 * HD * DM * 2);
  bf16_t* woT   = (bf16_t*)alloc((size_t)DM * DM * 2);
  bf16_t* qb    = (bf16_t*)alloc((size_t)BB * SEQ * DM * 2);
  bf16_t* kkb   = (bf16_t*)alloc((size_t)BB * SEQ * HD * 2);
  bf16_t* vTb   = (bf16_t*)alloc((size_t)BB * HD * SEQ * 2);
  bf16_t* aoutb = (bf16_t*)alloc((size_t)BB * SEQ * DM * 2);
  float*  maskA = (float*)alloc((size_t)BB * SEQ * 4);

  transpose_cast<<<dim3(DM / 32, DM / 32), 256, 0, stream>>>(wq, wqT, DM, DM);
  transpose_cast<<<dim3(128 / 32, DM / 32), 256, 0, stream>>>(wkv, wkvT, DM, 128);
  transpose_cast<<<dim3(DM / 32, DM / 32), 256, 0, stream>>>(wo, woT, DM, DM);
  row_prep<<<BB * SEQ, 256, 0, stream>>>(x, ln_w, ln_b, mask, xbf, xn, maskA);
  // q = xn @ wq, scaled by DH^-0.5
  gemm128<bf16_t><<<dim3(32, 8), 256, 0, stream>>>(xn, wqT, qb, BB * SEQ, DM, DM, 0.125f);
  // kv = x @ wkv -> K (B,SEQ,64) and V^T (B,64,SEQ)
  gemm_kv<<<dim3(32, 2), 256, 0, stream>>>(xbf, wkvT, kkb, vTb, BB * SEQ, 128, DM);
  flash_attn<<<dim3(SEQ / 64, BB * NHEAD), 256, 0, stream>>>(qb, kkb, vTb, attn_bias,
                                                             maskA, aoutb);
  // out = aout @ wo (fp32 output)
  gemm128<float><<<dim3(32, 8), 256, 0, stream>>>(aoutb, woT, out, BB * SEQ, DM, DM, 1.0f);
}